// Round 10
// baseline (1159.881 us; speedup 1.0000x reference)
//
#include <hip/hip_runtime.h>
#include <hip/hip_bf16.h>

#define EPS       0.05f
#define N_ITERS   20
#define NR        8192      // N == M
#define DIM       64
#define LOG2E     1.4426950408889634f
#define LN2       0.6931471805599453f
#define S2        (2.0f * LOG2E / EPS)   // 57.7078...
#define EPSLN2    (EPS * LN2)
#define NEGINF    (-1e30f)
#define NSPLIT    8                      // column splits (partials per side)

typedef __attribute__((ext_vector_type(8))) short short8;
typedef __attribute__((ext_vector_type(4))) float float4v;

#define GLD_LDS16(src, dst)                                              \
    __builtin_amdgcn_global_load_lds(                                    \
        (const __attribute__((address_space(1))) void*)(src),            \
        (__attribute__((address_space(3))) void*)(dst), 16, 0, 0)

__device__ __forceinline__ float wave_reduce_sum(float v) {
    #pragma unroll
    for (int m = 1; m < 64; m <<= 1) v += __shfl_xor(v, m, 64);
    return v;
}

// ---- setup: sums of a and b ------------------------------------------------
__global__ void sums_kernel(const float* __restrict__ a, const float* __restrict__ b,
                            float* __restrict__ sums) {
    __shared__ float red[32];
    int tid = threadIdx.x;
    float pa = 0.f, pb = 0.f;
    for (int i = tid; i < NR; i += blockDim.x) { pa += a[i]; pb += b[i]; }
    pa = wave_reduce_sum(pa);
    pb = wave_reduce_sum(pb);
    int wid = tid >> 6, ln = tid & 63;
    if (ln == 0) { red[wid] = pa; red[wid + 16] = pb; }
    __syncthreads();
    if (tid == 0) {
        float sa = 0.f, sb = 0.f;
        int nw = blockDim.x >> 6;
        for (int w = 0; w < nw; w++) { sa += red[w]; sb += red[w + 16]; }
        sums[0] = logf(sa); sums[1] = logf(sb); sums[2] = sa; sums[3] = sb;
    }
}

// ---- setup: bf16 copies (row-major + MFMA-stream layout), norms, weights ---
// thread = one 16B chunk: cid = row*8 + c  (c = k-chunk 0..7)
__global__ void prep_kernel(const float* __restrict__ x, const float* __restrict__ y,
                            const float* __restrict__ a, const float* __restrict__ b,
                            const float* __restrict__ sums,
                            short8* __restrict__ xr, short8* __restrict__ yr,
                            short8* __restrict__ xs, short8* __restrict__ ys,
                            float* __restrict__ x2, float* __restrict__ y2,
                            float* __restrict__ la2, float* __restrict__ lb2,
                            float2* __restrict__ Pb) {   // [NSPLIT][NR] g-partials
    int gid = blockIdx.x * 256 + threadIdx.x;
    bool isx = gid < NR * 8;
    int cid = isx ? gid : gid - NR * 8;
    int row = cid >> 3;
    int c   = cid & 7;
    const float4* src = (const float4*)(isx ? x : y);
    float4 v0 = src[row * 16 + c * 2];
    float4 v1 = src[row * 16 + c * 2 + 1];

    short8 st;
    st[0] = __bfloat16_as_short(__float2bfloat16(v0.x));
    st[1] = __bfloat16_as_short(__float2bfloat16(v0.y));
    st[2] = __bfloat16_as_short(__float2bfloat16(v0.z));
    st[3] = __bfloat16_as_short(__float2bfloat16(v0.w));
    st[4] = __bfloat16_as_short(__float2bfloat16(v1.x));
    st[5] = __bfloat16_as_short(__float2bfloat16(v1.y));
    st[6] = __bfloat16_as_short(__float2bfloat16(v1.z));
    st[7] = __bfloat16_as_short(__float2bfloat16(v1.w));

    (isx ? xr : yr)[row * 8 + c] = st;                       // row-major
    int T = row >> 4, ln = row & 15, f = c >> 2, q = c & 3;
    (isx ? xs : ys)[T * 128 + f * 64 + q * 16 + ln] = st;    // stream layout

    float sq = v0.x*v0.x + v0.y*v0.y + v0.z*v0.z + v0.w*v0.w
             + v1.x*v1.x + v1.y*v1.y + v1.z*v1.z + v1.w*v1.w;
    #pragma unroll
    for (int m = 1; m < 8; m <<= 1) sq += __shfl_xor(sq, m, 64);

    if (c == 0) {
        if (isx) {
            x2[row] = sq;
            la2[row] = (logf(a[row]) - sums[0]) * LOG2E;
        } else {
            y2[row] = sq;
            lb2[row] = (logf(b[row]) - sums[1]) * LOG2E;
            Pb[row] = make_float2(sq * (LOG2E / EPS), 1.0f);   // g = 0 initially
            #pragma unroll
            for (int k = 1; k < NSPLIT; k++)
                Pb[k * NR + row] = make_float2(NEGINF, 0.0f);
        }
    }
}

// 4-wide online LSE update: one state, 4 new z's
#define LSE4(acc, c4, mm, ss)                                            \
    {                                                                    \
        float z0 = fmaf(S2, (acc)[0], (c4).x);                           \
        float z1 = fmaf(S2, (acc)[1], (c4).y);                           \
        float z2 = fmaf(S2, (acc)[2], (c4).z);                           \
        float z3 = fmaf(S2, (acc)[3], (c4).w);                           \
        float zm = fmaxf(fmaxf(z0, z1), fmaxf(z2, z3));                  \
        float mn = fmaxf((mm), zm);                                      \
        float e  = __builtin_amdgcn_exp2f((mm) - mn);                    \
        float p  = (__builtin_amdgcn_exp2f(z0 - mn)                      \
                  + __builtin_amdgcn_exp2f(z1 - mn))                     \
                 + (__builtin_amdgcn_exp2f(z2 - mn)                      \
                  + __builtin_amdgcn_exp2f(z3 - mn));                    \
        (ss) = fmaf((ss), e, p);                                         \
        (mm) = mn;                                                       \
    }

// ---- one softmin sweep (eighth of the columns) -----------------------------
// R10: 256 rows/block (8 resident X row-tiles/wave) x 1024 cols; Y staged
// into LDS in 8 x 16KB chunks with THREE buffers and 2-chunk lookahead, raw
// s_barrier + per-wave vmcnt(1) so each fill has ~2 compute-chunks of cover.
// Per-CU requested bytes/pass: Y 128KB + Pin 64KB + X 32KB.
// Grid: 256 blocks = 32 row-groups x 8 col-splits; 1024 thr = 16 waves.
// Wave w: rh = w>>3 (128-row half, 8 tiles), cs = w&7 (16-col subtile/chunk).
__global__ __launch_bounds__(1024, 4) void pass_kernel(
        const short8* __restrict__ matXr,   // row-major resident (rows)
        const short8* __restrict__ matYs,   // stream-layout streamed (cols)
        const float2* __restrict__ Pin,     // [NSPLIT][NR] column-side partials
        const float* __restrict__ lw2col,   // [NR]
        float2* __restrict__ Pout) {        // [NSPLIT][NR] row-side partials
    __shared__ __attribute__((aligned(16))) char ybuf[3][16384];
    __shared__ __attribute__((aligned(16))) float cbl[1024];
    __shared__ float2 comb[256][9];         // [row][strip] (+1 pad)

    const int tid = threadIdx.x;
    const int bi  = blockIdx.x;
    const int q8  = bi & 7;                 // column eighth
    const int rg  = bi >> 3;                // row-group
    const int rb  = rg * 256;               // first row
    const int cb0 = q8 * 1024;              // first column

    const int w    = tid >> 6;        // wave 0..15
    const int lane = tid & 63;
    const int quad = lane >> 4;
    const int ln   = lane & 15;
    const int cs   = w & 7;           // col subtile within chunk
    const int rh   = w >> 3;          // row half (128 rows)

    const char* ysrc = (const char*)matYs + (size_t)cb0 * 128;
    const int c0 = rg & 7;            // rotated chunk order per row-group

    // kick chunk 0 staging immediately
    GLD_LDS16(ysrc + c0 * 16384 + w * 1024 + lane * 16, &ybuf[0][w * 1024]);
    __builtin_amdgcn_sched_barrier(0);

    // ---- prologue: merge 8 column partials -> cb for this block's 1024 cols
    {
        int j = cb0 + tid;                  // one column per thread
        float2 p[NSPLIT];
        float M = NEGINF;
        #pragma unroll
        for (int k = 0; k < NSPLIT; k++) {
            p[k] = Pin[k * NR + j];
            M = fmaxf(M, p[k].x);
        }
        float S = 0.f;
        #pragma unroll
        for (int k = 0; k < NSPLIT; k++)
            S += p[k].y * __builtin_amdgcn_exp2f(p[k].x - M);
        cbl[tid] = lw2col[j] - (M + __builtin_amdgcn_logf(S));
    }

    // resident X fragments (B-operand): 8 row-tiles, rows rb + rh*128 + t*16 + ln
    short8 xf0[8], xf1[8];
    #pragma unroll
    for (int t = 0; t < 8; t++) {
        int r = rb + rh * 128 + t * 16 + ln;
        xf0[t] = matXr[r * 8 + quad];
        xf1[t] = matXr[r * 8 + quad + 4];
    }

    // kick chunk 1 staging (last vm op before the loop)
    __builtin_amdgcn_sched_barrier(0);
    GLD_LDS16(ysrc + ((c0 + 1) & 7) * 16384 + w * 1024 + lane * 16, &ybuf[1][w * 1024]);
    __builtin_amdgcn_sched_barrier(0);

    float lm[8], ls[8];
    #pragma unroll
    for (int t = 0; t < 8; t++) { lm[t] = NEGINF; ls[t] = 0.f; }

    #pragma unroll
    for (int t = 0; t < 8; t++) {
        // wait: chunk t staged; one younger staging op may remain in flight.
        if (t < 7) __builtin_amdgcn_s_waitcnt(0x0071);  // vmcnt(1) lgkmcnt(0)
        else       __builtin_amdgcn_s_waitcnt(0x0070);  // vmcnt(0) lgkmcnt(0)
        __builtin_amdgcn_s_barrier();
        __builtin_amdgcn_sched_barrier(0);

        // stage chunk t+2 (buffer (t+2)%3 was fully consumed in iter t-1)
        if (t < 6) {
            GLD_LDS16(ysrc + ((c0 + t + 2) & 7) * 16384 + w * 1024 + lane * 16,
                      &ybuf[(t + 2) % 3][w * 1024]);
        }
        __builtin_amdgcn_sched_barrier(0);

        const int  sc   = (c0 + t) & 7;       // logical chunk (for cbl index)
        const char* base = &ybuf[t % 3][0];
        short8 ya0 = *(const short8*)(base + cs * 2048 + lane * 16);
        short8 ya1 = *(const short8*)(base + cs * 2048 + 1024 + lane * 16);
        float4 c4  = *(const float4*)(cbl + sc * 128 + cs * 16 + quad * 4);

        #pragma unroll
        for (int tt = 0; tt < 8; tt++) {
            float4v acc = {0.f, 0.f, 0.f, 0.f};
            acc = __builtin_amdgcn_mfma_f32_16x16x32_bf16(ya0, xf0[tt], acc, 0, 0, 0);
            acc = __builtin_amdgcn_mfma_f32_16x16x32_bf16(ya1, xf1[tt], acc, 0, 0, 0);
            LSE4(acc, c4, lm[tt], ls[tt]);
        }
    }

    // combine across the 4 quads (same ln = same output rows)
    #pragma unroll
    for (int mask = 16; mask < 64; mask <<= 1) {
        #pragma unroll
        for (int t = 0; t < 8; t++) {
            float mo = __shfl_xor(lm[t], mask, 64);
            float so = __shfl_xor(ls[t], mask, 64);
            float M  = fmaxf(lm[t], mo);
            ls[t] = ls[t] * __builtin_amdgcn_exp2f(lm[t] - M)
                  + so    * __builtin_amdgcn_exp2f(mo    - M);
            lm[t] = M;
        }
    }

    if (lane < 16) {
        #pragma unroll
        for (int t = 0; t < 8; t++)
            comb[rh * 128 + t * 16 + ln][cs] = make_float2(lm[t], ls[t]);
    }
    __syncthreads();

    // merge the 8 strips per row; write this eighth's partial
    if (tid < 256) {
        float2 c = comb[tid][0];
        float M = c.x, S = c.y;
        #pragma unroll
        for (int cc = 1; cc < 8; cc++) {
            float2 p = comb[tid][cc];
            float Mn = fmaxf(M, p.x);
            S = S * __builtin_amdgcn_exp2f(M - Mn)
              + p.y * __builtin_amdgcn_exp2f(p.x - Mn);
            M = Mn;
        }
        Pout[q8 * NR + rb + tid] = make_float2(M, S);
    }
}

// merged log2-LSE of NSPLIT partials for row i
__device__ __forceinline__ float merge8_full(const float2* __restrict__ P, int i) {
    float2 p[NSPLIT];
    float M = NEGINF;
    #pragma unroll
    for (int k = 0; k < NSPLIT; k++) {
        p[k] = P[k * NR + i];
        M = fmaxf(M, p[k].x);
    }
    float S = 0.f;
    #pragma unroll
    for (int k = 0; k < NSPLIT; k++)
        S += p[k].y * __builtin_amdgcn_exp2f(p[k].x - M);
    return M + __builtin_amdgcn_logf(S);   // log2 domain
}

// ---- final reduction: <a, f_fin>/sa + <b, g_fin>/sb ------------------------
__global__ void reduce_kernel(const float* __restrict__ a, const float* __restrict__ b,
                              const float* __restrict__ sums,
                              const float* __restrict__ x2, const float* __restrict__ y2,
                              const float2* __restrict__ Pff, const float2* __restrict__ Pgf,
                              float* __restrict__ out) {
    __shared__ float red[32];
    int tid = threadIdx.x;
    float da = 0.f, db = 0.f;
    for (int i = tid; i < NR; i += blockDim.x) {
        float fv = x2[i] - EPSLN2 * merge8_full(Pff, i);
        float gv = y2[i] - EPSLN2 * merge8_full(Pgf, i);
        da += a[i] * fv;
        db += b[i] * gv;
    }
    da = wave_reduce_sum(da);
    db = wave_reduce_sum(db);
    int wid = tid >> 6, ln = tid & 63;
    if (ln == 0) { red[wid] = da; red[wid + 16] = db; }
    __syncthreads();
    if (tid == 0) {
        float DA = 0.f, DB = 0.f;
        int nw = blockDim.x >> 6;
        for (int w = 0; w < nw; w++) { DA += red[w]; DB += red[w + 16]; }
        out[0] = DA / sums[2] + DB / sums[3];
    }
}

extern "C" void kernel_launch(void* const* d_in, const int* in_sizes, int n_in,
                              void* d_out, int out_size, void* d_ws, size_t ws_size,
                              hipStream_t stream) {
    const float* a = (const float*)d_in[0];
    const float* x = (const float*)d_in[1];
    const float* b = (const float*)d_in[2];
    const float* y = (const float*)d_in[3];

    char* ws = (char*)d_ws;
    short8* xr = (short8*)ws;                        // 1 MB row-major
    short8* yr = (short8*)(ws + (1 << 20));          // 1 MB
    short8* xs = (short8*)(ws + (2 << 20));          // 1 MB stream layout
    short8* ys = (short8*)(ws + (3 << 20));          // 1 MB
    float* fp  = (float*)(ws + (4 << 20));
    float* x2  = fp;
    float* y2  = fp + NR;
    float* la2 = fp + 2 * NR;
    float* lb2 = fp + 3 * NR;
    float2* P   = (float2*)(fp + 4 * NR);
    float2* Pf  = P;                          // f-side partials [NSPLIT][NR]
    float2* Pb  = P + NSPLIT * NR;            // g-side partials
    float2* Pff = P + 2 * NSPLIT * NR;        // final f partials
    float2* Pgf = P + 3 * NSPLIT * NR;        // final g partials
    float* sums = (float*)(P + 4 * NSPLIT * NR);

    sums_kernel<<<1, 1024, 0, stream>>>(a, b, sums);
    prep_kernel<<<(2 * NR * 8) / 256, 256, 0, stream>>>(x, y, a, b, sums,
                                                        xr, yr, xs, ys,
                                                        x2, y2, la2, lb2, Pb);

    for (int it = 0; it < N_ITERS; it++) {
        // f-update: rows = x-side (row-major), cols = y-side (stream)
        pass_kernel<<<256, 1024, 0, stream>>>(xr, ys, Pb, lb2, Pf);
        // g-update: rows = y-side, cols = x-side
        pass_kernel<<<256, 1024, 0, stream>>>(yr, xs, Pf, la2, Pb);
    }
    // final symmetric update from detached potentials
    pass_kernel<<<256, 1024, 0, stream>>>(xr, ys, Pb, lb2, Pff);
    pass_kernel<<<256, 1024, 0, stream>>>(yr, xs, Pf, la2, Pgf);

    reduce_kernel<<<1, 1024, 0, stream>>>(a, b, sums, x2, y2, Pff, Pgf, (float*)d_out);
}

// Round 11
// 859.075 us; speedup vs baseline: 1.3502x; 1.3502x over previous
//
#include <hip/hip_runtime.h>
#include <hip/hip_bf16.h>

#define EPS       0.05f
#define N_ITERS   20
#define NR        8192      // N == M
#define DIM       64
#define LOG2E     1.4426950408889634f
#define LN2       0.6931471805599453f
#define S2        (2.0f * LOG2E / EPS)   // 57.7078...
#define EPSLN2    (EPS * LN2)
#define NEGINF    (-1e30f)
#define NSPLIT    16                     // column splits (partials per side)

typedef __attribute__((ext_vector_type(8))) short short8;
typedef __attribute__((ext_vector_type(4))) float float4v;

#define GLD_LDS16(src, dst)                                              \
    __builtin_amdgcn_global_load_lds(                                    \
        (const __attribute__((address_space(1))) void*)(src),            \
        (__attribute__((address_space(3))) void*)(dst), 16, 0, 0)

__device__ __forceinline__ float wave_reduce_sum(float v) {
    #pragma unroll
    for (int m = 1; m < 64; m <<= 1) v += __shfl_xor(v, m, 64);
    return v;
}

// merged log2-LSE of NSPLIT partials for row/col i
__device__ __forceinline__ float merge16_l(const float2* __restrict__ P, int i) {
    float2 p[NSPLIT];
    float M = NEGINF;
    #pragma unroll
    for (int k = 0; k < NSPLIT; k++) {
        p[k] = P[k * NR + i];
        M = fmaxf(M, p[k].x);
    }
    float S = 0.f;
    #pragma unroll
    for (int k = 0; k < NSPLIT; k++)
        S += p[k].y * __builtin_amdgcn_exp2f(p[k].x - M);
    return M + __builtin_amdgcn_logf(S);   // log2 domain
}

// ---- setup: sums of a and b ------------------------------------------------
__global__ void sums_kernel(const float* __restrict__ a, const float* __restrict__ b,
                            float* __restrict__ sums) {
    __shared__ float red[32];
    int tid = threadIdx.x;
    float pa = 0.f, pb = 0.f;
    for (int i = tid; i < NR; i += blockDim.x) { pa += a[i]; pb += b[i]; }
    pa = wave_reduce_sum(pa);
    pb = wave_reduce_sum(pb);
    int wid = tid >> 6, ln = tid & 63;
    if (ln == 0) { red[wid] = pa; red[wid + 16] = pb; }
    __syncthreads();
    if (tid == 0) {
        float sa = 0.f, sb = 0.f;
        int nw = blockDim.x >> 6;
        for (int w = 0; w < nw; w++) { sa += red[w]; sb += red[w + 16]; }
        sums[0] = logf(sa); sums[1] = logf(sb); sums[2] = sa; sums[3] = sb;
    }
}

// ---- setup: bf16 stream-layout copies, norms, weights, initial partials ----
// thread = one 16B chunk: cid = row*8 + c  (c = k-chunk 0..7)
// Stream layout per 16-row tile T: frag f (0/1), slot lane=q*16+ln holds
// rows T*16+ln, k = f*32 + q*8 .. +8  -> contiguous 2KB per tile.
__global__ void prep_kernel(const float* __restrict__ x, const float* __restrict__ y,
                            const float* __restrict__ a, const float* __restrict__ b,
                            const float* __restrict__ sums,
                            short8* __restrict__ xs, short8* __restrict__ ys,
                            float* __restrict__ x2, float* __restrict__ y2,
                            float* __restrict__ la2, float* __restrict__ lb2,
                            float2* __restrict__ Pb) {   // [NSPLIT][NR] g-partials
    int gid = blockIdx.x * 256 + threadIdx.x;
    bool isx = gid < NR * 8;
    int cid = isx ? gid : gid - NR * 8;
    int row = cid >> 3;
    int c   = cid & 7;
    const float4* src = (const float4*)(isx ? x : y);
    float4 v0 = src[row * 16 + c * 2];
    float4 v1 = src[row * 16 + c * 2 + 1];

    short8 st;
    st[0] = __bfloat16_as_short(__float2bfloat16(v0.x));
    st[1] = __bfloat16_as_short(__float2bfloat16(v0.y));
    st[2] = __bfloat16_as_short(__float2bfloat16(v0.z));
    st[3] = __bfloat16_as_short(__float2bfloat16(v0.w));
    st[4] = __bfloat16_as_short(__float2bfloat16(v1.x));
    st[5] = __bfloat16_as_short(__float2bfloat16(v1.y));
    st[6] = __bfloat16_as_short(__float2bfloat16(v1.z));
    st[7] = __bfloat16_as_short(__float2bfloat16(v1.w));

    int T = row >> 4, ln = row & 15, f = c >> 2, q = c & 3;
    (isx ? xs : ys)[T * 128 + f * 64 + q * 16 + ln] = st;    // stream layout

    float sq = v0.x*v0.x + v0.y*v0.y + v0.z*v0.z + v0.w*v0.w
             + v1.x*v1.x + v1.y*v1.y + v1.z*v1.z + v1.w*v1.w;
    #pragma unroll
    for (int m = 1; m < 8; m <<= 1) sq += __shfl_xor(sq, m, 64);

    if (c == 0) {
        if (isx) {
            x2[row] = sq;
            la2[row] = (logf(a[row]) - sums[0]) * LOG2E;
        } else {
            y2[row] = sq;
            lb2[row] = (logf(b[row]) - sums[1]) * LOG2E;
            Pb[row] = make_float2(sq * (LOG2E / EPS), 1.0f);   // g = 0 initially
            #pragma unroll
            for (int k = 1; k < NSPLIT; k++)
                Pb[k * NR + row] = make_float2(NEGINF, 0.0f);
        }
    }
}

// 4-wide online LSE update: one state, 4 new z's
#define LSE4(acc, c4, mm, ss)                                            \
    {                                                                    \
        float z0 = fmaf(S2, (acc)[0], (c4).x);                           \
        float z1 = fmaf(S2, (acc)[1], (c4).y);                           \
        float z2 = fmaf(S2, (acc)[2], (c4).z);                           \
        float z3 = fmaf(S2, (acc)[3], (c4).w);                           \
        float zm = fmaxf(fmaxf(z0, z1), fmaxf(z2, z3));                  \
        float mn = fmaxf((mm), zm);                                      \
        float e  = __builtin_amdgcn_exp2f((mm) - mn);                    \
        float p  = (__builtin_amdgcn_exp2f(z0 - mn)                      \
                  + __builtin_amdgcn_exp2f(z1 - mn))                     \
                 + (__builtin_amdgcn_exp2f(z2 - mn)                      \
                  + __builtin_amdgcn_exp2f(z3 - mn));                    \
        (ss) = fmaf((ss), e, p);                                         \
        (mm) = mn;                                                       \
    }

// ---- one softmin sweep (1/16 of the columns) -------------------------------
// R11: everything deduped through LDS. Block = 512 rows x 512 cols; X staged
// once (64 KB LDS, read back as fragments via ds_read_b128), Y double-buffered
// 16 KB chunks (4 chunks). Per-CU requested bytes: X 64K + Y 64K + Pin 64K.
// Grid 256 = 16 row-groups x 16 col-splits. Wave w: rq=w>>2 (128-row quarter,
// 8 tiles held in regs), cst=w&3 (32-col strip of each chunk).
__global__ __launch_bounds__(1024, 4) void pass_kernel(
        const short8* __restrict__ matXs,   // stream layout, resident (rows)
        const short8* __restrict__ matYs,   // stream layout, streamed (cols)
        const float2* __restrict__ Pin,     // [NSPLIT][NR] column-side partials
        const float* __restrict__ lw2col,   // [NR]
        float2* __restrict__ Pout) {        // [NSPLIT][NR] row-side partials
    __shared__ __attribute__((aligned(16))) char xlds[65536];
    __shared__ __attribute__((aligned(16))) char ybuf[2][16384];
    __shared__ __attribute__((aligned(16))) float cbl[512];
    __shared__ float2 comb[512][5];         // [row][strip] (+1 pad)

    const int tid = threadIdx.x;
    const int bi  = blockIdx.x;
    const int q   = bi & 15;                // column split
    const int rg  = bi >> 4;                // row-group
    const int rb  = rg * 512;
    const int cb0 = q * 512;

    const int w    = tid >> 6;        // wave 0..15
    const int lane = tid & 63;
    const int quad = lane >> 4;
    const int ln   = lane & 15;
    const int cst  = w & 3;           // 32-col strip within chunk
    const int rq   = w >> 2;          // 128-row quarter

    // ---- issue ALL X staging + first two Y chunks up front (async) ----
    const char* xsrc = (const char*)matXs + (size_t)rb * 128;   // 64 KB contiguous
    #pragma unroll
    for (int r = 0; r < 4; r++)
        GLD_LDS16(xsrc + r * 16384 + tid * 16, &xlds[r * 16384 + w * 1024]);
    const char* ysrc = (const char*)matYs + (size_t)cb0 * 128;  // 64 KB contiguous
    GLD_LDS16(ysrc + 0 * 16384 + tid * 16, &ybuf[0][w * 1024]);
    GLD_LDS16(ysrc + 1 * 16384 + tid * 16, &ybuf[1][w * 1024]);
    __builtin_amdgcn_sched_barrier(0);

    // ---- prologue: merge 16 column partials -> cbl (threads 0..511) ----
    if (tid < 512) {
        int j = cb0 + tid;
        cbl[tid] = lw2col[j] - merge16_l(Pin, j);
    }
    __builtin_amdgcn_sched_barrier(0);
    // X + Y0 staged (Y1 may remain in flight); cbl ds_writes drained
    __builtin_amdgcn_s_waitcnt(0x0071);     // vmcnt(1) lgkmcnt(0)
    __builtin_amdgcn_s_barrier();
    __builtin_amdgcn_sched_barrier(0);

    // ---- X fragments from LDS: 8 row-tiles (rows rb + rq*128 + t*16 + ln) --
    short8 xf0[8], xf1[8];
    {
        const char* xw = &xlds[(rq * 8) * 2048];
        #pragma unroll
        for (int t = 0; t < 8; t++) {
            xf0[t] = *(const short8*)(xw + t * 2048 + lane * 16);
            xf1[t] = *(const short8*)(xw + t * 2048 + 1024 + lane * 16);
        }
    }

    float lm[8], ls[8];
    #pragma unroll
    for (int t = 0; t < 8; t++) { lm[t] = NEGINF; ls[t] = 0.f; }

    #pragma unroll
    for (int c = 0; c < 4; c++) {
        const char* base = &ybuf[c & 1][0];
        #pragma unroll
        for (int uu = 0; uu < 2; uu++) {
            const int u = cst * 2 + uu;       // 16-col subtile within chunk
            short8 ya0 = *(const short8*)(base + u * 2048 + lane * 16);
            short8 ya1 = *(const short8*)(base + u * 2048 + 1024 + lane * 16);
            float4 c4  = *(const float4*)(cbl + (c * 8 + u) * 16 + quad * 4);

            #pragma unroll
            for (int tt = 0; tt < 8; tt++) {
                float4v acc = {0.f, 0.f, 0.f, 0.f};
                acc = __builtin_amdgcn_mfma_f32_16x16x32_bf16(ya0, xf0[tt], acc, 0, 0, 0);
                acc = __builtin_amdgcn_mfma_f32_16x16x32_bf16(ya1, xf1[tt], acc, 0, 0, 0);
                LSE4(acc, c4, lm[tt], ls[tt]);
            }
        }
        if (c < 3) {
            __builtin_amdgcn_sched_barrier(0);
            __builtin_amdgcn_s_barrier();       // all waves done reading buf[c&1]
            __builtin_amdgcn_sched_barrier(0);
            if (c < 2)                           // refill the freed buffer
                GLD_LDS16(ysrc + (c + 2) * 16384 + tid * 16, &ybuf[c & 1][w * 1024]);
            __builtin_amdgcn_sched_barrier(0);
            if (c < 2) __builtin_amdgcn_s_waitcnt(0x0071);  // chunk c+1 landed
            else       __builtin_amdgcn_s_waitcnt(0x0070);  // chunk 3 landed
            __builtin_amdgcn_s_barrier();
            __builtin_amdgcn_sched_barrier(0);
        }
    }

    // combine across the 4 quads (same ln = same output rows)
    #pragma unroll
    for (int mask = 16; mask < 64; mask <<= 1) {
        #pragma unroll
        for (int t = 0; t < 8; t++) {
            float mo = __shfl_xor(lm[t], mask, 64);
            float so = __shfl_xor(ls[t], mask, 64);
            float M  = fmaxf(lm[t], mo);
            ls[t] = ls[t] * __builtin_amdgcn_exp2f(lm[t] - M)
                  + so    * __builtin_amdgcn_exp2f(mo    - M);
            lm[t] = M;
        }
    }

    __syncthreads();   // xlds/ybuf reads done; comb region safe (distinct anyway)
    if (lane < 16) {
        #pragma unroll
        for (int t = 0; t < 8; t++)
            comb[rq * 128 + t * 16 + ln][cst] = make_float2(lm[t], ls[t]);
    }
    __syncthreads();

    // merge the 4 strips per row; write this split's partial
    if (tid < 512) {
        float2 cc0 = comb[tid][0];
        float M = cc0.x, S = cc0.y;
        #pragma unroll
        for (int cc = 1; cc < 4; cc++) {
            float2 p = comb[tid][cc];
            float Mn = fmaxf(M, p.x);
            S = S * __builtin_amdgcn_exp2f(M - Mn)
              + p.y * __builtin_amdgcn_exp2f(p.x - Mn);
            M = Mn;
        }
        Pout[q * NR + rb + tid] = make_float2(M, S);
    }
}

// ---- reduction stage 1: per-128-row partial dots (64 blocks) ---------------
__global__ void reduce1_kernel(const float* __restrict__ a, const float* __restrict__ b,
                               const float* __restrict__ x2, const float* __restrict__ y2,
                               const float2* __restrict__ Pff, const float2* __restrict__ Pgf,
                               float2* __restrict__ red2) {
    __shared__ float red[4];
    int tid = threadIdx.x;                    // 256 thr = 4 waves
    int r   = blockIdx.x * 128 + (tid & 127);
    bool gs = tid >= 128;                     // waves 0-1: f side, 2-3: g side
    float L  = merge16_l(gs ? Pgf : Pff, r);
    float sq = gs ? y2[r] : x2[r];
    float wv = gs ? b[r]  : a[r];
    float v  = wv * (sq - EPSLN2 * L);
    v = wave_reduce_sum(v);
    if ((tid & 63) == 0) red[tid >> 6] = v;
    __syncthreads();
    if (tid == 0) red2[blockIdx.x] = make_float2(red[0] + red[1], red[2] + red[3]);
}

// ---- reduction stage 2 -----------------------------------------------------
__global__ void reduce2_kernel(const float* __restrict__ sums,
                               const float2* __restrict__ red2,
                               float* __restrict__ out) {
    int tid = threadIdx.x;   // 64
    float2 v = red2[tid];
    float da = wave_reduce_sum(v.x);
    float db = wave_reduce_sum(v.y);
    if (tid == 0) out[0] = da / sums[2] + db / sums[3];
}

extern "C" void kernel_launch(void* const* d_in, const int* in_sizes, int n_in,
                              void* d_out, int out_size, void* d_ws, size_t ws_size,
                              hipStream_t stream) {
    const float* a = (const float*)d_in[0];
    const float* x = (const float*)d_in[1];
    const float* b = (const float*)d_in[2];
    const float* y = (const float*)d_in[3];

    char* ws = (char*)d_ws;
    short8* xs = (short8*)ws;                        // 1 MB stream layout
    short8* ys = (short8*)(ws + (1 << 20));          // 1 MB
    float* fp  = (float*)(ws + (2 << 20));
    float* x2  = fp;
    float* y2  = fp + NR;
    float* la2 = fp + 2 * NR;
    float* lb2 = fp + 3 * NR;
    float2* P   = (float2*)(fp + 4 * NR);
    float2* Pf  = P;                          // f-side partials [NSPLIT][NR]
    float2* Pb  = P + NSPLIT * NR;            // g-side partials
    float2* Pff = P + 2 * NSPLIT * NR;        // final f partials
    float2* Pgf = P + 3 * NSPLIT * NR;        // final g partials
    float2* red2 = P + 4 * NSPLIT * NR;       // 64 entries
    float* sums  = (float*)(red2 + 64);

    sums_kernel<<<1, 1024, 0, stream>>>(a, b, sums);
    prep_kernel<<<(2 * NR * 8) / 256, 256, 0, stream>>>(x, y, a, b, sums,
                                                        xs, ys,
                                                        x2, y2, la2, lb2, Pb);

    for (int it = 0; it < N_ITERS; it++) {
        // f-update: rows = x-side, cols = y-side biased by g-partials
        pass_kernel<<<256, 1024, 0, stream>>>(xs, ys, Pb, lb2, Pf);
        // g-update: rows = y-side, cols = x-side biased by f-partials
        pass_kernel<<<256, 1024, 0, stream>>>(ys, xs, Pf, la2, Pb);
    }
    // final symmetric update from detached potentials
    pass_kernel<<<256, 1024, 0, stream>>>(xs, ys, Pb, lb2, Pff);
    pass_kernel<<<256, 1024, 0, stream>>>(ys, xs, Pf, la2, Pgf);

    reduce1_kernel<<<64, 256, 0, stream>>>(a, b, x2, y2, Pff, Pgf, red2);
    reduce2_kernel<<<1, 64, 0, stream>>>(sums, red2, (float*)d_out);
}